// Round 9
// baseline (142.081 us; speedup 1.0000x reference)
//
#include <hip/hip_runtime.h>

typedef __bf16 bf16;
typedef __bf16 bf16x8 __attribute__((ext_vector_type(8)));
typedef float  f32x4  __attribute__((ext_vector_type(4)));

#define T_SEQ   2048
#define D_HEAD  64
#define NH      16
#define BH      32
#define C_EMB   1024
#define WS_STRIDE (BH * T_SEQ * D_HEAD)   // 4,194,304 elems per plane
#define XN (4096 * 1024)
#define WN (3072 * 1024)
#define WS_NEEDED ((size_t)(3 * WS_STRIDE + XN + WN) * 2)
#define CVT_GRID 3584

__device__ __forceinline__ bf16x8 cvt8(float4 a, float4 b) {
    bf16x8 r;
    r[0] = (__bf16)a.x; r[1] = (__bf16)a.y; r[2] = (__bf16)a.z; r[3] = (__bf16)a.w;
    r[4] = (__bf16)b.x; r[5] = (__bf16)b.y; r[6] = (__bf16)b.z; r[7] = (__bf16)b.w;
    return r;
}

__device__ __forceinline__ void gl_lds16(const bf16* g, bf16* l) {
    __builtin_amdgcn_global_load_lds(
        (const __attribute__((address_space(1))) unsigned int*)g,
        (__attribute__((address_space(3))) unsigned int*)l,
        16, 0, 0);
}

__device__ __forceinline__ unsigned pack_bf16(float a, float b) {
    union { __bf16 h[2]; unsigned u; } pk;
    pk.h[0] = (__bf16)a; pk.h[1] = (__bf16)b;
    return pk.u;
}

// ---------------------------------------------------------------------------
// Kernel 0: fp32 -> bf16 convert of x and W.
// ---------------------------------------------------------------------------
__global__ __launch_bounds__(256) void cvt_bf16(
    const float* __restrict__ x, const float* __restrict__ W,
    bf16* __restrict__ xb, bf16* __restrict__ wb)
{
    const int t = blockIdx.x * 256 + threadIdx.x;   // 917504 threads
    const float* src; bf16* dst; int base;
    if (t < XN / 8) { src = x; dst = xb; base = t * 8; }
    else           { src = W; dst = wb; base = (t - XN / 8) * 8; }
    float4 a = *(const float4*)(src + base);
    float4 b = *(const float4*)(src + base + 4);
    *(bf16x8*)(dst + base) = cvt8(a, b);
}

// ---------------------------------------------------------------------------
// Kernel 1: qkv = xb @ wb^T + b.  128x192 tile, BK=64, 4 waves (1Mx4N),
// grid 32x16 = 512 blocks = 2 blocks/CU (80 KB LDS). 4-phase double-buffered
// HALF schedule, counted s_waitcnt vmcnt(10). (unchanged this round)
// ---------------------------------------------------------------------------
#define LDA(d, qi) {                                                          \
    const bf16* abase_ = Sh + (d)*8192 + (qi)*4096 + l15*64;                  \
    _Pragma("unroll")                                                         \
    for (int ii_ = 0; ii_ < 4; ii_++) {                                       \
        _Pragma("unroll")                                                     \
        for (int dk_ = 0; dk_ < 2; dk_++)                                     \
            aF[ii_][dk_] = *(const bf16x8*)(abase_ + ii_*1024                 \
                                            + (((dk_*4 + l4) ^ k7) * 8));     \
    }                                                                         \
}

#define LDB(d) {                                                              \
    const bf16* bbase_ = Sh + 16384 + (d)*12288 + (w*48 + l15)*64;            \
    _Pragma("unroll")                                                         \
    for (int jj_ = 0; jj_ < 3; jj_++) {                                       \
        _Pragma("unroll")                                                     \
        for (int dk_ = 0; dk_ < 2; dk_++)                                     \
            bF[jj_][dk_] = *(const bf16x8*)(bbase_ + jj_*1024                 \
                                            + (((dk_*4 + l4) ^ k7) * 8));     \
    }                                                                         \
}

#define STA(d, qi, s, ko) gl_lds16(                                           \
    aSrc + (size_t)((qi)*64 + (s)*32) * 1024 + (ko),                          \
    Sh + (d)*8192 + (qi)*4096 + (s)*2048 + w*512)

#define STB(d, u, ko) gl_lds16(                                               \
    bSrc + (size_t)((u)*32) * 1024 + (ko),                                    \
    Sh + 16384 + (d)*12288 + (u)*2048 + w*512)

#define MMA2(qi, ja, jb) {                                                    \
    __builtin_amdgcn_s_setprio(1);                                            \
    _Pragma("unroll")                                                         \
    for (int dk_ = 0; dk_ < 2; dk_++) {                                       \
        _Pragma("unroll")                                                     \
        for (int ii_ = 0; ii_ < 4; ii_++) {                                   \
            acc[(qi)*4 + ii_][ja] = __builtin_amdgcn_mfma_f32_16x16x32_bf16(  \
                aF[ii_][dk_], bF[ja][dk_], acc[(qi)*4 + ii_][ja], 0, 0, 0);   \
            acc[(qi)*4 + ii_][jb] = __builtin_amdgcn_mfma_f32_16x16x32_bf16(  \
                aF[ii_][dk_], bF[jb][dk_], acc[(qi)*4 + ii_][jb], 0, 0, 0);   \
        }                                                                     \
    }                                                                         \
    __builtin_amdgcn_s_setprio(0);                                            \
}

#define MMA1(qi, ja) {                                                        \
    __builtin_amdgcn_s_setprio(1);                                            \
    _Pragma("unroll")                                                         \
    for (int dk_ = 0; dk_ < 2; dk_++) {                                       \
        _Pragma("unroll")                                                     \
        for (int ii_ = 0; ii_ < 4; ii_++)                                     \
            acc[(qi)*4 + ii_][ja] = __builtin_amdgcn_mfma_f32_16x16x32_bf16(  \
                aF[ii_][dk_], bF[ja][dk_], acc[(qi)*4 + ii_][ja], 0, 0, 0);   \
    }                                                                         \
    __builtin_amdgcn_s_setprio(0);                                            \
}

#define BAR   __builtin_amdgcn_s_barrier()
#define LGKM0 asm volatile("s_waitcnt lgkmcnt(0)" ::: "memory")

// One K-tile (4 phases) on buffer d, staging tile t+2 at k-offset sk.
#define HALF(d, sk)                                                           \
    /* P0 */                                                                  \
    LDA(d, 0) LDB(d)                                                          \
    BAR; LGKM0;                                                               \
    MMA2(0, 0, 1)                                                             \
    BAR;                                                                      \
    /* P1: B + A-qi0 died at P0 */                                            \
    STB(d, 0, sk); STB(d, 1, sk); STB(d, 2, sk);                              \
    STB(d, 3, sk); STB(d, 4, sk); STB(d, 5, sk);                              \
    STA(d, 0, 0, sk); STA(d, 0, 1, sk);                                       \
    BAR;                                                                      \
    MMA1(0, 2)                                                                \
    BAR;                                                                      \
    /* P2 */                                                                  \
    LDA(d, 1)                                                                 \
    BAR; LGKM0;                                                               \
    MMA2(1, 0, 1)                                                             \
    BAR;                                                                      \
    /* P3: A-qi1 died at P2 */                                                \
    STA(d, 1, 0, sk); STA(d, 1, 1, sk);                                       \
    BAR;                                                                      \
    MMA1(1, 2)                                                                \
    asm volatile("s_waitcnt vmcnt(10)" ::: "memory");                         \
    BAR;

__global__ __launch_bounds__(256, 2) void qkv_gemm5(
    const bf16* __restrict__ xb, const bf16* __restrict__ wb,
    const float* __restrict__ bias, bf16* __restrict__ ws)
{
    __shared__ bf16 Sh[40960];   // A: 2x8192, B: 2x12288 elems (80 KiB)

    const int tid  = threadIdx.x;
    const int lane = tid & 63;
    const int w    = tid >> 6;            // 0..3 (N-split wave grid)
    const int l15  = lane & 15, l4 = lane >> 4;
    const int k7   = l15 & 7;
    const int l8   = lane >> 3;           // staging row-in-wave
    const int csw  = (lane & 7) ^ l8;     // pre-swizzled source chunk

    const int swz = (blockIdx.x & 7) * 64 + (blockIdx.x >> 3);  // T1, bijective
    const int bm  = swz >> 4, bn = swz & 15;   // bm 0..31, bn 0..15

    const bf16* aSrc = xb + (size_t)(bm * 128 + w * 8 + l8) * 1024 + csw * 8;
    const bf16* bSrc = wb + (size_t)(bn * 192 + w * 8 + l8) * 1024 + csw * 8;

    f32x4 acc[8][3];
#pragma unroll
    for (int i = 0; i < 8; i++)
#pragma unroll
        for (int j = 0; j < 3; j++) acc[i][j] = (f32x4){0.f, 0.f, 0.f, 0.f};

    bf16x8 aF[4][2], bF[3][2];

    // ---- prologue: stage tile0 -> buf0, tile1 -> buf1 (10 loads each) ----
    STA(0,0,0,0);  STA(0,0,1,0);  STA(0,1,0,0);  STA(0,1,1,0);
    STB(0,0,0);    STB(0,1,0);    STB(0,2,0);
    STB(0,3,0);    STB(0,4,0);    STB(0,5,0);
    STA(1,0,0,64); STA(1,0,1,64); STA(1,1,0,64); STA(1,1,1,64);
    STB(1,0,64);   STB(1,1,64);   STB(1,2,64);
    STB(1,3,64);   STB(1,4,64);   STB(1,5,64);
    asm volatile("s_waitcnt vmcnt(10)" ::: "memory");   // tile0 landed
    BAR;

    // ---- main loop: 8 iterations x 2 K-tiles (K=1024, BK=64) ----
    for (int it = 0; it < 8; ++it) {
        const int sk0 = (it < 7 ? (2 * it + 2) : 15) * 64;  // clamp: re-stage
        const int sk1 = (it < 7 ? (2 * it + 3) : 15) * 64;  // tile15 harmlessly
        HALF(0, sk0)
        HALF(1, sk1)
    }
    asm volatile("s_waitcnt vmcnt(0)" ::: "memory");   // drain garbage stages
    BAR;                                               // LDS now reusable

    // ---- epilogue: per-16-col-frag; +bias (+0.125 for q) ----
    float bv[3];
#pragma unroll
    for (int ff = 0; ff < 3; ff++)
        bv[ff] = bias[bn * 192 + w * 48 + ff * 16 + l15];

    const int bi    = bm >> 4;                     // batch (block-uniform)
    const int tBase = (bm & 15) * 128;             // t-offset of block
    bf16* Wl = Sh + w * 8192;                      // private 16 KiB slice
    bf16* vt = ws + 2 * (size_t)WS_STRIDE;

    // store phase: each frag 2048 elems in Wl
#pragma unroll
    for (int ff = 0; ff < 3; ff++) {
        const int col0 = bn * 192 + w * 48 + ff * 16;
        const int wch  = col0 >> 10;               // plane (wave-uniform)
        const float qs = (wch == 0) ? 0.125f : 1.0f;
        if (wch < 2) {
            // [lt][16] layout, chunk-bit XOR on (lt)
#pragma unroll
            for (int i = 0; i < 8; i++)
#pragma unroll
                for (int r = 0; r < 4; r++) {
                    const int lt = i * 16 + l4 * 4 + r;
                    const int dl = l15;
                    Wl[ff * 2048 + lt * 16 + (((dl >> 3) ^ lt) & 1) * 8 + (dl & 7)]
                        = (__bf16)((acc[i][ff][r] + bv[ff]) * qs);
                }
        } else {
            // [dl][128] layout, 16-chunk XOR rotation on (ct ^ dl)
#pragma unroll
            for (int i = 0; i < 8; i++)
#pragma unroll
                for (int p = 0; p < 2; p++) {
                    const int lt0 = i * 16 + l4 * 4 + 2 * p;
                    const int ct  = lt0 >> 3;
                    const int dl  = l15;
                    *(unsigned*)&Wl[ff * 2048 + dl * 128
                                    + ((ct ^ dl) & 15) * 8 + (lt0 & 7)]
                        = pack_bf16(acc[i][ff][2 * p] + bv[ff],
                                    acc[i][ff][2 * p + 1] + bv[ff]);
                }
        }
    }
    __syncthreads();

    // readback + global store phase
#pragma unroll
    for (int ff = 0; ff < 3; ff++) {
        const int col0 = bn * 192 + w * 48 + ff * 16;
        const int wch  = col0 >> 10;
        const int cc   = col0 & 1023;
        const int hh   = cc >> 6;
        const int dd0  = cc & 63;
        if (wch < 2) {
#pragma unroll
            for (int it = 0; it < 4; it++) {
                const int lt = it * 32 + (lane >> 1);
                const int c2 = lane & 1;
                bf16x8 v8 = *(const bf16x8*)&Wl[ff * 2048 + lt * 16
                                                + ((c2 ^ lt) & 1) * 8];
                *(bf16x8*)&ws[(size_t)wch * WS_STRIDE
                              + ((size_t)(bi * NH + hh) * T_SEQ + tBase + lt) * D_HEAD
                              + dd0 + c2 * 8] = v8;
            }
        } else {
#pragma unroll
            for (int e = 0; e < 4; e++) {
                const int dl = e * 4 + l4;
                const int ct = l15;
                bf16x8 v8 = *(const bf16x8*)&Wl[ff * 2048 + dl * 128
                                                + ((ct ^ dl) & 15) * 8];
                *(bf16x8*)&vt[((size_t)(bi * NH + hh) * D_HEAD + dd0 + dl) * T_SEQ
                              + tBase + ct * 8] = v8;
            }
        }
    }
}

// ---------------------------------------------------------------------------
// Kernel 1 fallback (ws too small): register-convert GEMM, scalar epilogue.
// ---------------------------------------------------------------------------
__global__ __launch_bounds__(256) void qkv_gemm(
    const float* __restrict__ x, const float* __restrict__ W,
    const float* __restrict__ bias, bf16* __restrict__ ws)
{
    __shared__ bf16 As[128 * 40];
    __shared__ bf16 Bs[128 * 40];

    const int tid  = threadIdx.x;
    const int lane = tid & 63;
    const int w    = tid >> 6;
    const int wm   = w >> 1, wn = w & 1;
    const int l15  = lane & 15, l4 = lane >> 4;
    const int bm   = blockIdx.x / 24, bn = blockIdx.x % 24;

    const int srow = tid >> 1;
    const int scol = (tid & 1) * 16;
    const float* xg = x + (size_t)(bm * 128 + srow) * 1024 + scol;
    const float* wg = W + (size_t)(bn * 128 + srow) * 1024 + scol;
    bf16* asw = &As[srow * 40 + scol];
    bf16* bsw = &Bs[srow * 40 + scol];

    f32x4 acc[4][4];
#pragma unroll
    for (int i = 0; i < 4; i++)
#pragma unroll
        for (int j = 0; j < 4; j++) acc[i][j] = (f32x4){0.f, 0.f, 0.f, 0.f};

    float bv[4];
#pragma unroll
    for (int j = 0; j < 4; j++) bv[j] = bias[bn * 128 + wn * 64 + j * 16 + l15];

    for (int kk = 0; kk < 32; ++kk) {
        const float* xp = xg + kk * 32;
        const float* wp = wg + kk * 32;
        float4 a0 = *(const float4*)(xp + 0);
        float4 a1 = *(const float4*)(xp + 4);
        float4 a2 = *(const float4*)(xp + 8);
        float4 a3 = *(const float4*)(xp + 12);
        float4 b0 = *(const float4*)(wp + 0);
        float4 b1 = *(const float4*)(wp + 4);
        float4 b2 = *(const float4*)(wp + 8);
        float4 b3 = *(const float4*)(wp + 12);

        __syncthreads();
        *(bf16x8*)(asw + 0) = cvt8(a0, a1);
        *(bf16x8*)(asw + 8) = cvt8(a2, a3);
        *(bf16x8*)(bsw + 0) = cvt8(b0, b1);
        *(bf16x8*)(bsw + 8) = cvt8(b2, b3);
        __syncthreads();

        bf16x8 aF[4], bF[4];
#pragma unroll
        for (int s = 0; s < 4; s++) {
            aF[s] = *(const bf16x8*)&As[(wm * 64 + s * 16 + l15) * 40 + l4 * 8];
            bF[s] = *(const bf16x8*)&Bs[(wn * 64 + s * 16 + l15) * 40 + l4 * 8];
        }
#pragma unroll
        for (int i = 0; i < 4; i++)
#pragma unroll
            for (int j = 0; j < 4; j++)
                acc[i][j] = __builtin_amdgcn_mfma_f32_16x16x32_bf16(
                    aF[i], bF[j], acc[i][j], 0, 0, 0);
    }

#pragma unroll
    for (int i = 0; i < 4; i++) {
#pragma unroll
        for (int j = 0; j < 4; j++) {
            const int n     = bn * 128 + wn * 64 + j * 16 + l15;
            const int which = n >> 10;
            const int cc    = n & 1023;
            const int h     = cc >> 6, d = cc & 63;
            const float qs  = (which == 0) ? 0.125f : 1.0f;
#pragma unroll
            for (int r = 0; r < 4; r++) {
                const int m  = bm * 128 + wm * 64 + i * 16 + l4 * 4 + r;
                const int bi = m >> 11, t = m & 2047;
                const int bh = bi * NH + h;
                const float v = (acc[i][j][r] + bv[j]) * qs;
                size_t idx;
                if (which == 2)
                    idx = 2 * (size_t)WS_STRIDE + ((size_t)bh * D_HEAD + d) * T_SEQ + t;
                else
                    idx = (size_t)which * WS_STRIDE + ((size_t)bh * T_SEQ + t) * D_HEAD + d;
                ws[idx] = (__bf16)v;
            }
        }
    }
}

// ---------------------------------------------------------------------------
// Kernel 2: causal ReLU attention v11 — KVBLK=64, K+V double-buffered,
// single-vmcnt two-barrier step, full residency.
// 1024 blocks x 256 threads (4 waves, 16 q-rows/wave, 64 q-rows/block).
// LDS 32 KB (Kb 2x8 + Vb 2x8) -> all 1024 blocks co-resident (4/CU,
// 16 waves/CU vs v10's 12). Per step: issue K(jt+1)+V(jt+1) (4 gl_lds/
// wave) -> s_waitcnt vmcnt(4) retires exactly K(jt)+V(jt) -> barrier ->
// QK (8 MFMA) + PV (8 MFMA) back-to-back -> barrier (WAR). Swizzles
// re-derived for 64-wide tiles, applied both sides:
//   K: stored pos = c ^ (r&7) ^ (((r>>3)&3)<<1)  (source term (w*2+e)&3)
//   V: stored pos = c ^ (r&7)   (8 chunks/row; read ct = kk*4+qd)
// keyb = jt*64 + 32m + 8qd + 4h2 (m in 0..1). Diagonal masking inherent
// (64-wide last tile). Work-descending dispatch s = 31-u.
// ---------------------------------------------------------------------------
#define KSTAGE(jt_, p_) {                                                     \
    _Pragma("unroll")                                                         \
    for (int e_ = 0; e_ < 2; e_++) {                                          \
        const int rb_ = w * 16 + e_ * 8;                                      \
        gl_lds16(kg + (size_t)((jt_) * 64 + rb_ + ksub) * 64                  \
                    + ((kc ^ ksub ^ (((w * 2 + e_) & 3) << 1)) * 8),          \
                 &Kb[p_][rb_ * 64]);                                          \
    }                                                                         \
}

#define VSTAGE(jt_, p_) {                                                     \
    _Pragma("unroll")                                                         \
    for (int e_ = 0; e_ < 2; e_++) {                                          \
        const int rb_ = w * 16 + e_ * 8;                                      \
        gl_lds16(vt + (size_t)(rb_ + ksub) * T_SEQ + (jt_) * 64               \
                    + ((kc ^ ksub) * 8),                                      \
                 &Vb[p_][rb_ * 64]);                                          \
    }                                                                         \
}

__global__ __launch_bounds__(256, 4) void attn(
    const bf16* __restrict__ ws, float* __restrict__ out)
{
    __shared__ bf16 Kb[2][64 * 64];   // [key][d], pos = c ^ (r&7) ^ ((r>>3)&3)<<1
    __shared__ bf16 Vb[2][64 * 64];   // [d][key], pos = c ^ (r&7)

    const int tid  = threadIdx.x;
    const int lane = tid & 63;
    const int w    = tid >> 6;           // 0..3
    const int l15  = lane & 15, qd = lane >> 4;

    const int bh = blockIdx.x & 31;      // XCD = blk&7 -> bh mod 8 affinity
    const int u  = blockIdx.x >> 5;      // 0..31
    const int s  = 31 - u;               // big q-slices dispatch first
    const int nj = s + 1;                // 64-key tiles
    const int qb = s * 64;               // block q-row base

    const bf16* qg = ws + (size_t)bh * (T_SEQ * D_HEAD);
    const bf16* kg = ws + WS_STRIDE + (size_t)bh * (T_SEQ * D_HEAD);
    const bf16* vt = ws + 2 * (size_t)WS_STRIDE + (size_t)bh * (D_HEAD * T_SEQ);
    const int b = bh >> 4, h = bh & 15;

    // staging lane constants
    const int ksub = lane >> 3;          // row-in-issue 0..7
    const int kc   = lane & 7;           // stored chunk position

    // K fragment-read lane constants (conflict-free positions)
    const int krow0 = 8 * (l15 >> 2) + (l15 & 3);                  // row base
    const int pos00 = qd ^ (l15 & 3) ^ ((l15 >> 2) << 1);          // 0..7
    const int kbO0  = krow0 * 64 + pos00 * 8;
    const int kbO1  = krow0 * 64 + (pos00 ^ 4) * 8;

    // Q fragments (pre-scaled by 1/8), live across whole loop
    bf16x8 qF[2];
#pragma unroll
    for (int dk = 0; dk < 2; dk++)
        qF[dk] = *(const bf16x8*)(qg
            + (qb + w * 16 + l15) * 64 + dk * 32 + qd * 8);

    f32x4 o[4];
#pragma unroll
    for (int sd = 0; sd < 4; sd++) o[sd] = (f32x4){0.f, 0.f, 0.f, 0.f};

    // ---- prologue: stage tile 0 into buffer 0 (4 gl_lds/wave) ----
    KSTAGE(0, 0);
    VSTAGE(0, 0);

    for (int jt = 0; jt < nj; ++jt) {
        const int p = jt & 1;
        // issue next tile early; counted wait retires exactly tile jt
        if (jt + 1 < nj) {
            KSTAGE(jt + 1, p ^ 1);
            VSTAGE(jt + 1, p ^ 1);
            asm volatile("s_waitcnt vmcnt(4)" ::: "memory");  // tile jt landed
        } else {
            asm volatile("s_waitcnt vmcnt(0)" ::: "memory");
        }
        BAR;   // tile jt visible to all waves

        const bf16* kb0 = &Kb[p][kbO0];
        const bf16* kb1 = &Kb[p][kbO1];

        // ---- QK (permuted rows) + relu + mask + pack ----
        const bool need_mask = (jt == nj - 1);
        unsigned PK[4][2];
#pragma unroll
        for (int m = 0; m < 2; m++) {
            bf16x8 kf[2][2];
            kf[0][0] = *(const bf16x8*)(kb0 + m * 2048);        // kn=2m, lo
            kf[0][1] = *(const bf16x8*)(kb1 + m * 2048);        // kn=2m, hi
            kf[1][0] = *(const bf16x8*)(kb1 + m * 2048 + 256);  // kn=2m+1, lo
            kf[1][1] = *(const bf16x8*)(kb0 + m * 2048 + 256);  // kn=2m+1, hi
#pragma unroll
            for (int h2 = 0; h2 < 2; h2++) {
                const int kn = 2 * m + h2;
                f32x4 s0 = {0.f, 0.f, 0.f, 0.f};
                __builtin_amdgcn_s_setprio(1);
                s0 = __builtin_amdgcn_mfma_f32_16x16x32_bf16(kf[h2][0], qF[0], s0, 0, 0, 0);
                s0 = __builtin_amdgcn_mfma_f32_16x16x32_bf16(kf[h2][1], qF[1], s0, 0, 0, 0);
                __builtin_amdgcn_s_setprio(0);
                const int keyb = jt * 64 + 32 * m + 8 * qd + 4 * h2;
                float v[4];
#pragma unroll
                for (int r = 0; r < 4; r++) v[r] = fmaxf(s0[r], 0.f);
                if (need_mask) {   // wave-uniform: last (diagonal) tile only
                    const int q = qb + w * 16 + l15;
#pragma unroll
                    for (int r = 0; r < 4; r++)
                        if (q < keyb + r) v[r] = 0.f;
                }
                PK[kn][0] = pack_bf16(v[0], v[1]);
                PK[kn][1] = pack_bf16(v[2], v[3]);
            }
        }

        // ---- PV: pF direct from this lane's PK dwords; vF from LDS ----
#pragma unroll
        for (int kk = 0; kk < 2; kk++) {
            union { unsigned dw[4]; bf16x8 v; } uu;
            uu.dw[0] = PK[2 * kk + 0][0];
            uu.dw[1] = PK[2 * kk + 0][1];
            uu.dw[2] = PK[2 * kk + 1][0];
            uu.dw[3] = PK[2 * kk + 1][1];
            const bf16x8 pF = uu.v;
            __builtin_amdgcn_s_setprio(1);
#pragma unroll
            for (int sd = 0; sd < 4; sd++) {
                bf16x8 vf = *(const bf16x8*)&Vb[p][(sd * 16 + l15) * 64
                                                   + (((kk * 4 + qd) ^ (l15 & 7)) * 8)];
                o[sd] = __builtin_amdgcn_mfma_f32_16x16x32_bf16(pF, vf, o[sd], 0, 0, 0);
            }
            __builtin_amdgcn_s_setprio(0);
        }

        BAR;   // WAR: next step's staging overwrites the buffers just read
    }

    // ---- plain-store O (exclusive q-row ownership) ----
#pragma unroll
    for (int sd = 0; sd < 4; sd++) {
        const int d = sd * 16 + l15;
#pragma unroll
        for (int r = 0; r < 4; r++) {
            const int t = qb + w * 16 + qd * 4 + r;
            out[((size_t)b * T_SEQ + t) * C_EMB + h * 64 + d] = o[sd][r];
        }
    }
}

extern "C" void kernel_launch(void* const* d_in, const int* in_sizes, int n_in,
                              void* d_out, int out_size, void* d_ws, size_t ws_size,
                              hipStream_t stream) {
    const float* x    = (const float*)d_in[0];
    const float* W    = (const float*)d_in[1];
    const float* bias = (const float*)d_in[2];
    float* out        = (float*)d_out;
    bf16*  ws         = (bf16*)d_ws;

    if (ws_size >= WS_NEEDED) {
        bf16* xb = ws + 3 * (size_t)WS_STRIDE;
        bf16* wb = xb + XN;
        cvt_bf16<<<dim3(CVT_GRID), dim3(256), 0, stream>>>(x, W, xb, wb);
        qkv_gemm5<<<dim3(512), dim3(256), 0, stream>>>(xb, wb, bias, ws);
    } else {
        qkv_gemm<<<dim3(768), dim3(256), 0, stream>>>(x, W, bias, ws);
    }
    attn<<<dim3(1024), dim3(256), 0, stream>>>(ws, out);
}

// Round 10
// 136.153 us; speedup vs baseline: 1.0435x; 1.0435x over previous
//
#include <hip/hip_runtime.h>

typedef __bf16 bf16;
typedef __bf16 bf16x8 __attribute__((ext_vector_type(8)));
typedef float  f32x4  __attribute__((ext_vector_type(4)));

#define T_SEQ   2048
#define D_HEAD  64
#define NH      16
#define BH      32
#define C_EMB   1024
#define WS_STRIDE (BH * T_SEQ * D_HEAD)   // 4,194,304 elems per plane
#define XN (4096 * 1024)
#define WN (3072 * 1024)
#define WS_NEEDED ((size_t)(3 * WS_STRIDE + XN + WN) * 2)
#define CVT_GRID 3584

__device__ __forceinline__ bf16x8 cvt8(float4 a, float4 b) {
    bf16x8 r;
    r[0] = (__bf16)a.x; r[1] = (__bf16)a.y; r[2] = (__bf16)a.z; r[3] = (__bf16)a.w;
    r[4] = (__bf16)b.x; r[5] = (__bf16)b.y; r[6] = (__bf16)b.z; r[7] = (__bf16)b.w;
    return r;
}

__device__ __forceinline__ void gl_lds16(const bf16* g, bf16* l) {
    __builtin_amdgcn_global_load_lds(
        (const __attribute__((address_space(1))) unsigned int*)g,
        (__attribute__((address_space(3))) unsigned int*)l,
        16, 0, 0);
}

__device__ __forceinline__ unsigned pack_bf16(float a, float b) {
    union { __bf16 h[2]; unsigned u; } pk;
    pk.h[0] = (__bf16)a; pk.h[1] = (__bf16)b;
    return pk.u;
}

// ---------------------------------------------------------------------------
// Kernel 0: fp32 -> bf16 convert of x and W.
// ---------------------------------------------------------------------------
__global__ __launch_bounds__(256) void cvt_bf16(
    const float* __restrict__ x, const float* __restrict__ W,
    bf16* __restrict__ xb, bf16* __restrict__ wb)
{
    const int t = blockIdx.x * 256 + threadIdx.x;   // 917504 threads
    const float* src; bf16* dst; int base;
    if (t < XN / 8) { src = x; dst = xb; base = t * 8; }
    else           { src = W; dst = wb; base = (t - XN / 8) * 8; }
    float4 a = *(const float4*)(src + base);
    float4 b = *(const float4*)(src + base + 4);
    *(bf16x8*)(dst + base) = cvt8(a, b);
}

// ---------------------------------------------------------------------------
// Kernel 1: qkv = xb @ wb^T + b.  128x192 tile, BK=64, 4 waves (1Mx4N),
// grid 512 blocks = 2 blocks/CU (80 KB LDS). v6: the 4-phase schedule is
// MERGED into one phase per K-tile: read ALL tile frags (22 ds_read_b128
// -> aF0/aF1/bF), lgkmcnt(0), ONE barrier, issue all 10 stages for tile
// t+2, 48-MFMA cluster, vmcnt(10), ONE barrier. 2 barriers + 1 vmcnt per
// K-tile vs gemm5's 8 barriers + 2 lgkm drains — 4x fewer sync points,
// 48 MFMA per sync section. WAR: stages into buf d issue only after the
// barrier following every wave's reads of buf d. vmcnt algebra unchanged
// (prologue 20-issue wait-10; each HALF issues 10, waits to 10). VGPR
// ~215 (aF0+aF1 64, bF 24, acc 96) — fits 2 waves/SIMD (LDS-capped).
// ---------------------------------------------------------------------------
#define LDAq(d, qi, dst) {                                                    \
    const bf16* abase_ = Sh + (d)*8192 + (qi)*4096 + l15*64;                  \
    _Pragma("unroll")                                                         \
    for (int ii_ = 0; ii_ < 4; ii_++) {                                       \
        _Pragma("unroll")                                                     \
        for (int dk_ = 0; dk_ < 2; dk_++)                                     \
            dst[ii_][dk_] = *(const bf16x8*)(abase_ + ii_*1024                \
                                            + (((dk_*4 + l4) ^ k7) * 8));     \
    }                                                                         \
}

#define LDB(d) {                                                              \
    const bf16* bbase_ = Sh + 16384 + (d)*12288 + (w*48 + l15)*64;            \
    _Pragma("unroll")                                                         \
    for (int jj_ = 0; jj_ < 3; jj_++) {                                       \
        _Pragma("unroll")                                                     \
        for (int dk_ = 0; dk_ < 2; dk_++)                                     \
            bF[jj_][dk_] = *(const bf16x8*)(bbase_ + jj_*1024                 \
                                            + (((dk_*4 + l4) ^ k7) * 8));     \
    }                                                                         \
}

#define STA(d, qi, s, ko) gl_lds16(                                           \
    aSrc + (size_t)((qi)*64 + (s)*32) * 1024 + (ko),                          \
    Sh + (d)*8192 + (qi)*4096 + (s)*2048 + w*512)

#define STB(d, u, ko) gl_lds16(                                               \
    bSrc + (size_t)((u)*32) * 1024 + (ko),                                    \
    Sh + 16384 + (d)*12288 + (u)*2048 + w*512)

#define MMAQ(qi, src) {                                                       \
    _Pragma("unroll")                                                         \
    for (int dk_ = 0; dk_ < 2; dk_++) {                                       \
        _Pragma("unroll")                                                     \
        for (int ii_ = 0; ii_ < 4; ii_++) {                                   \
            _Pragma("unroll")                                                 \
            for (int jj_ = 0; jj_ < 3; jj_++)                                 \
                acc[(qi)*4 + ii_][jj_] =                                      \
                    __builtin_amdgcn_mfma_f32_16x16x32_bf16(                  \
                        src[ii_][dk_], bF[jj_][dk_],                          \
                        acc[(qi)*4 + ii_][jj_], 0, 0, 0);                     \
        }                                                                     \
    }                                                                         \
}

#define BAR   __builtin_amdgcn_s_barrier()
#define LGKM0 asm volatile("s_waitcnt lgkmcnt(0)" ::: "memory")

// One K-tile, single merged phase, staging tile t+2 at k-offset sk.
#define HALF(d, sk)                                                           \
    LDAq(d, 0, aF0) LDAq(d, 1, aF1) LDB(d)                                    \
    LGKM0;                                                                    \
    BAR;   /* all waves' reads of buf d complete -> safe to overwrite */      \
    STB(d, 0, sk); STB(d, 1, sk); STB(d, 2, sk);                              \
    STB(d, 3, sk); STB(d, 4, sk); STB(d, 5, sk);                              \
    STA(d, 0, 0, sk); STA(d, 0, 1, sk);                                       \
    STA(d, 1, 0, sk); STA(d, 1, 1, sk);                                       \
    __builtin_amdgcn_s_setprio(1);                                            \
    MMAQ(0, aF0)                                                              \
    MMAQ(1, aF1)                                                              \
    __builtin_amdgcn_s_setprio(0);                                            \
    asm volatile("s_waitcnt vmcnt(10)" ::: "memory");  /* tile t+1 landed */  \
    BAR;

__global__ __launch_bounds__(256, 2) void qkv_gemm6(
    const bf16* __restrict__ xb, const bf16* __restrict__ wb,
    const float* __restrict__ bias, bf16* __restrict__ ws)
{
    __shared__ bf16 Sh[40960];   // A: 2x8192, B: 2x12288 elems (80 KiB)

    const int tid  = threadIdx.x;
    const int lane = tid & 63;
    const int w    = tid >> 6;            // 0..3 (N-split wave grid)
    const int l15  = lane & 15, l4 = lane >> 4;
    const int k7   = l15 & 7;
    const int l8   = lane >> 3;           // staging row-in-wave
    const int csw  = (lane & 7) ^ l8;     // pre-swizzled source chunk

    const int swz = (blockIdx.x & 7) * 64 + (blockIdx.x >> 3);  // T1, bijective
    const int bm  = swz >> 4, bn = swz & 15;   // bm 0..31, bn 0..15

    const bf16* aSrc = xb + (size_t)(bm * 128 + w * 8 + l8) * 1024 + csw * 8;
    const bf16* bSrc = wb + (size_t)(bn * 192 + w * 8 + l8) * 1024 + csw * 8;

    f32x4 acc[8][3];
#pragma unroll
    for (int i = 0; i < 8; i++)
#pragma unroll
        for (int j = 0; j < 3; j++) acc[i][j] = (f32x4){0.f, 0.f, 0.f, 0.f};

    bf16x8 aF0[4][2], aF1[4][2], bF[3][2];

    // ---- prologue: stage tile0 -> buf0, tile1 -> buf1 (10 loads each) ----
    STA(0,0,0,0);  STA(0,0,1,0);  STA(0,1,0,0);  STA(0,1,1,0);
    STB(0,0,0);    STB(0,1,0);    STB(0,2,0);
    STB(0,3,0);    STB(0,4,0);    STB(0,5,0);
    STA(1,0,0,64); STA(1,0,1,64); STA(1,1,0,64); STA(1,1,1,64);
    STB(1,0,64);   STB(1,1,64);   STB(1,2,64);
    STB(1,3,64);   STB(1,4,64);   STB(1,5,64);
    asm volatile("s_waitcnt vmcnt(10)" ::: "memory");   // tile0 landed
    BAR;

    // ---- main loop: 8 iterations x 2 K-tiles (K=1024, BK=64) ----
    for (int it = 0; it < 8; ++it) {
        const int sk0 = (it < 7 ? (2 * it + 2) : 15) * 64;  // clamp: re-stage
        const int sk1 = (it < 7 ? (2 * it + 3) : 15) * 64;  // tile15 harmlessly
        HALF(0, sk0)
        HALF(1, sk1)
    }
    asm volatile("s_waitcnt vmcnt(0)" ::: "memory");   // drain garbage stages
    BAR;                                               // LDS now reusable

    // ---- epilogue: per-16-col-frag; +bias (+0.125 for q) ----
    float bv[3];
#pragma unroll
    for (int ff = 0; ff < 3; ff++)
        bv[ff] = bias[bn * 192 + w * 48 + ff * 16 + l15];

    const int bi    = bm >> 4;                     // batch (block-uniform)
    const int tBase = (bm & 15) * 128;             // t-offset of block
    bf16* Wl = Sh + w * 8192;                      // private 16 KiB slice
    bf16* vt = ws + 2 * (size_t)WS_STRIDE;

    // store phase: each frag 2048 elems in Wl
#pragma unroll
    for (int ff = 0; ff < 3; ff++) {
        const int col0 = bn * 192 + w * 48 + ff * 16;
        const int wch  = col0 >> 10;               // plane (wave-uniform)
        const float qs = (wch == 0) ? 0.125f : 1.0f;
        if (wch < 2) {
            // [lt][16] layout, chunk-bit XOR on (lt)
#pragma unroll
            for (int i = 0; i < 8; i++)
#pragma unroll
                for (int r = 0; r < 4; r++) {
                    const int lt = i * 16 + l4 * 4 + r;
                    const int dl = l15;
                    Wl[ff * 2048 + lt * 16 + (((dl >> 3) ^ lt) & 1) * 8 + (dl & 7)]
                        = (__bf16)((acc[i][ff][r] + bv[ff]) * qs);
                }
        } else {
            // [dl][128] layout, 16-chunk XOR rotation on (ct ^ dl)
#pragma unroll
            for (int i = 0; i < 8; i++)
#pragma unroll
                for (int p = 0; p < 2; p++) {
                    const int lt0 = i * 16 + l4 * 4 + 2 * p;
                    const int ct  = lt0 >> 3;
                    const int dl  = l15;
                    *(unsigned*)&Wl[ff * 2048 + dl * 128
                                    + ((ct ^ dl) & 15) * 8 + (lt0 & 7)]
                        = pack_bf16(acc[i][ff][2 * p] + bv[ff],
                                    acc[i][ff][2 * p + 1] + bv[ff]);
                }
        }
    }
    __syncthreads();

    // readback + global store phase
#pragma unroll
    for (int ff = 0; ff < 3; ff++) {
        const int col0 = bn * 192 + w * 48 + ff * 16;
        const int wch  = col0 >> 10;
        const int cc   = col0 & 1023;
        const int hh   = cc >> 6;
        const int dd0  = cc & 63;
        if (wch < 2) {
#pragma unroll
            for (int it = 0; it < 4; it++) {
                const int lt = it * 32 + (lane >> 1);
                const int c2 = lane & 1;
                bf16x8 v8 = *(const bf16x8*)&Wl[ff * 2048 + lt * 16
                                                + ((c2 ^ lt) & 1) * 8];
                *(bf16x8*)&ws[(size_t)wch * WS_STRIDE
                              + ((size_t)(bi * NH + hh) * T_SEQ + tBase + lt) * D_HEAD
                              + dd0 + c2 * 8] = v8;
            }
        } else {
#pragma unroll
            for (int e = 0; e < 4; e++) {
                const int dl = e * 4 + l4;
                const int ct = l15;
                bf16x8 v8 = *(const bf16x8*)&Wl[ff * 2048 + dl * 128
                                                + ((ct ^ dl) & 15) * 8];
                *(bf16x8*)&vt[((size_t)(bi * NH + hh) * D_HEAD + dd0 + dl) * T_SEQ
                              + tBase + ct * 8] = v8;
            }
        }
    }
}

// ---------------------------------------------------------------------------
// Kernel 1 fallback (ws too small): register-convert GEMM, scalar epilogue.
// ---------------------------------------------------------------------------
__global__ __launch_bounds__(256) void qkv_gemm(
    const float* __restrict__ x, const float* __restrict__ W,
    const float* __restrict__ bias, bf16* __restrict__ ws)
{
    __shared__ bf16 As[128 * 40];
    __shared__ bf16 Bs[128 * 40];

    const int tid  = threadIdx.x;
    const int lane = tid & 63;
    const int w    = tid >> 6;
    const int wm   = w >> 1, wn = w & 1;
    const int l15  = lane & 15, l4 = lane >> 4;
    const int bm   = blockIdx.x / 24, bn = blockIdx.x % 24;

    const int srow = tid >> 1;
    const int scol = (tid & 1) * 16;
    const float* xg = x + (size_t)(bm * 128 + srow) * 1024 + scol;
    const float* wg = W + (size_t)(bn * 128 + srow) * 1024 + scol;
    bf16* asw = &As[srow * 40 + scol];
    bf16* bsw = &Bs[srow * 40 + scol];

    f32x4 acc[4][4];
#pragma unroll
    for (int i = 0; i < 4; i++)
#pragma unroll
        for (int j = 0; j < 4; j++) acc[i][j] = (f32x4){0.f, 0.f, 0.f, 0.f};

    float bv[4];
#pragma unroll
    for (int j = 0; j < 4; j++) bv[j] = bias[bn * 128 + wn * 64 + j * 16 + l15];

    for (int kk = 0; kk < 32; ++kk) {
        const float* xp = xg + kk * 32;
        const float* wp = wg + kk * 32;
        float4 a0 = *(const float4*)(xp + 0);
        float4 a1 = *(const float4*)(xp + 4);
        float4 a2 = *(const float4*)(xp + 8);
        float4 a3 = *(const float4*)(xp + 12);
        float4 b0 = *(const float4*)(wp + 0);
        float4 b1 = *(const float4*)(wp + 4);
        float4 b2 = *(const float4*)(wp + 8);
        float4 b3 = *(const float4*)(wp + 12);

        __syncthreads();
        *(bf16x8*)(asw + 0) = cvt8(a0, a1);
        *(bf16x8*)(asw + 8) = cvt8(a2, a3);
        *(bf16x8*)(bsw + 0) = cvt8(b0, b1);
        *(bf16x8*)(bsw + 8) = cvt8(b2, b3);
        __syncthreads();

        bf16x8 aF[4], bF[4];
#pragma unroll
        for (int s = 0; s < 4; s++) {
            aF[s] = *(const bf16x8*)&As[(wm * 64 + s * 16 + l15) * 40 + l4 * 8];
            bF[s] = *(const bf16x8*)&Bs[(wn * 64 + s * 16 + l15) * 40 + l4 * 8];
        }
#pragma unroll
        for (int i = 0; i < 4; i++)
#pragma unroll
            for (int j = 0; j < 4; j++)
                acc[i][j] = __builtin_amdgcn_mfma_f32_16x16x32_bf16(
                    aF[i], bF[j], acc[i][j], 0, 0, 0);
    }

#pragma unroll
    for (int i = 0; i < 4; i++) {
#pragma unroll
        for (int j = 0; j < 4; j++) {
            const int n     = bn * 128 + wn * 64 + j * 16 + l15;
            const int which = n >> 10;
            const int cc    = n & 1023;
            const int h     = cc >> 6, d = cc & 63;
            const float qs  = (which == 0) ? 0.125f : 1.0f;
#pragma unroll
            for (int r = 0; r < 4; r++) {
                const int m  = bm * 128 + wm * 64 + i * 16 + l4 * 4 + r;
                const int bi = m >> 11, t = m & 2047;
                const int bh = bi * NH + h;
                const float v = (acc[i][j][r] + bv[j]) * qs;
                size_t idx;
                if (which == 2)
                    idx = 2 * (size_t)WS_STRIDE + ((size_t)bh * D_HEAD + d) * T_SEQ + t;
                else
                    idx = (size_t)which * WS_STRIDE + ((size_t)bh * T_SEQ + t) * D_HEAD + d;
                ws[idx] = (__bf16)v;
            }
        }
    }
}

// ---------------------------------------------------------------------------
// Kernel 2: causal ReLU attention v10 (reverted to best-known, R8 config).
// 1024 blocks x 256 threads (4 waves, 16 q-rows/wave). LDS 48 KB
// (Kb dbuf 2x16 + Vts 16) -> 3 blocks/CU = 12 waves/CU. Counted
// vmcnt(8)/(4) with K-prefetch; both-sides swizzles; diagonal mMax skip.
// ---------------------------------------------------------------------------
#define KSTAGE(jt_, p_) {                                                     \
    _Pragma("unroll")                                                         \
    for (int e_ = 0; e_ < 4; e_++) {                                          \
        const int rb_ = w * 32 + e_ * 8;                                      \
        gl_lds16(kg + (size_t)((jt_) * 128 + rb_ + ksub) * 64                 \
                    + ((kc ^ ksub ^ (e_ << 1)) * 8),                          \
                 &Kb[p_][rb_ * 64]);                                          \
    }                                                                         \
}

#define VSTAGE(jt_) {                                                         \
    _Pragma("unroll")                                                         \
    for (int e_ = 0; e_ < 4; e_++) {                                          \
        const int rb_ = w * 16 + e_ * 4;                                      \
        const int sw_ = (rb_ & 12) + vsub;   /* == (row & 15) */              \
        gl_lds16(vt + (size_t)(rb_ + vsub) * T_SEQ + (jt_) * 128              \
                    + ((vc ^ sw_) * 8),                                       \
                 &Vts[rb_ * 128]);                                            \
    }                                                                         \
}

__global__ __launch_bounds__(256) void attn(
    const bf16* __restrict__ ws, float* __restrict__ out)
{
    __shared__ bf16 Kb[2][128 * 64];   // [key][d], chunk ^ (r&7) ^ ((r>>3)&3)<<1
    __shared__ bf16 Vts[64 * 128];     // [d][key], 16-chunk XOR swizzle

    const int tid  = threadIdx.x;
    const int lane = tid & 63;
    const int w    = tid >> 6;           // 0..3
    const int l15  = lane & 15, qd = lane >> 4;

    const int bh = blockIdx.x & 31;      // XCD = blk&7 -> bh mod 8 affinity
    const int u  = blockIdx.x >> 5;      // 0..31
    const int s  = 31 - u;               // big q-slices dispatch first
    const int qt = s >> 1;               // q-tile 0..15
    const int hs = s & 1;                // half within q-tile
    const int nj = qt + 1;
    const int qb = s * 64;               // block q-row base

    const bf16* qg = ws + (size_t)bh * (T_SEQ * D_HEAD);
    const bf16* kg = ws + WS_STRIDE + (size_t)bh * (T_SEQ * D_HEAD);
    const bf16* vt = ws + 2 * (size_t)WS_STRIDE + (size_t)bh * (D_HEAD * T_SEQ);
    const int b = bh >> 4, h = bh & 15;

    // staging lane constants
    const int ksub = lane >> 3;          // K: row-in-issue 0..7
    const int kc   = lane & 7;           // K: stored chunk position
    const int vsub = qd;                 // V: row-in-issue 0..3
    const int vc   = l15;                // V: stored chunk position

    // K fragment-read lane constants (conflict-free positions)
    const int krow0 = 8 * (l15 >> 2) + (l15 & 3);                  // row base
    const int pos00 = qd ^ (l15 & 3) ^ ((l15 >> 2) << 1);          // 0..7
    const int kbO0  = krow0 * 64 + pos00 * 8;
    const int kbO1  = krow0 * 64 + (pos00 ^ 4) * 8;

    // Q fragments (pre-scaled by 1/8), live across whole loop
    bf16x8 qF[2];
#pragma unroll
    for (int dk = 0; dk < 2; dk++)
        qF[dk] = *(const bf16x8*)(qg
            + (qb + w * 16 + l15) * 64 + dk * 32 + qd * 8);

    f32x4 o[4];
#pragma unroll
    for (int sd = 0; sd < 4; sd++) o[sd] = (f32x4){0.f, 0.f, 0.f, 0.f};

    // ---- prologue: stage K tile 0 into buffer 0 ----
    KSTAGE(0, 0);

    for (int jt = 0; jt < nj; ++jt) {
        const int p = jt & 1;
        const bool more = (jt + 1 < nj);
        // V(jt) first (mid-step counted wait retires it), then K(jt+1).
        VSTAGE(jt);
        if (more) {
            KSTAGE(jt + 1, p ^ 1);
            asm volatile("s_waitcnt vmcnt(8)" ::: "memory");  // K(jt) landed
        } else {
            asm volatile("s_waitcnt vmcnt(4)" ::: "memory");  // K(jt) landed
        }
        BAR;   // K tile jt visible to all waves

        const bf16* kb0 = &Kb[p][kbO0];
        const bf16* kb1 = &Kb[p][kbO1];

        // ---- QK (permuted rows) + relu + mask + pack ----
        const bool need_mask = (jt == nj - 1);
        // diagonal tile, even half-slice: keys >= qt*128+64 fully masked
        const int mMax = (need_mask && hs == 0) ? 2 : 4;
        unsigned PK[8][2];
#pragma unroll
        for (int m = 0; m < 4; m++) {
            if (m < mMax) {
                bf16x8 kf[2][2];
                kf[0][0] = *(const bf16x8*)(kb0 + m * 2048);        // kn=2m, lo
                kf[0][1] = *(const bf16x8*)(kb1 + m * 2048);        // kn=2m, hi
                kf[1][0] = *(const bf16x8*)(kb1 + m * 2048 + 256);  // kn=2m+1, lo
                kf[1][1] = *(const bf16x8*)(kb0 + m * 2048 + 256);  // kn=2m+1, hi
#pragma unroll
                for (int h2 = 0; h2 < 2; h2++) {
                    const int kn = 2 * m + h2;
                    f32x4 s0 = {0.f, 0.f, 0.f, 0.f};
                    __builtin_amdgcn_s_setprio(1);
                    s0 = __builtin_amdgcn_mfma_f32_16x16x32_bf16(kf[h2][0], qF[0], s0, 0, 0, 0);
                    s0 = __builtin_amdgcn_mfma_f32_16x16x32_bf16(kf[h2][1], qF[1], s0, 0, 0, 0);
                    __builtin_amdgcn_s_setprio(0);
                    const int keyb = jt * 128 + 32 * m + 8 * qd + 4 * h2;
                    float v[4];
#pragma unroll
                    for (int r = 0; r < 4; r++) v[r] = fmaxf(s0[r], 0.f);
                    if (need_mask) {   // wave-uniform: last step only
                        const int q = qb + w * 16 + l15;
#pragma unroll
                        for (int r = 0; r < 4; r++)
                            if (q < keyb + r) v[r] = 0.f;
                    }
                    PK[kn][0] = pack_bf16(v[0], v[1]);
                    PK[kn][1] = pack_bf16(v[2], v[3]);
                }
            }
        }

        // V landed under QK; counted wait keeps K(jt+1) in flight
        if (more) asm volatile("s_waitcnt vmcnt(4)" ::: "memory");
        else      asm volatile("s_waitcnt vmcnt(0)" ::: "memory");
        BAR;   // V tile jt visible to all waves

        // ---- PV: pF direct from this lane's PK dwords; vF from LDS ----
#pragma unroll
        for (int kk = 0; kk < 4; kk++) {
            if (kk < mMax) {
                union { unsigned dw[4]; bf16x8 v; } uu;
                uu.dw[0] = PK[2 * kk + 0][0];
                uu.dw[1] = PK[2 * kk + 0][1];
                uu.dw[2] = PK[2 * kk + 1][0];
                uu.dw[3] = PK[2 * kk + 1][1];
                const bf16x8 pF = uu.v;
                __builtin_amdgcn_s_setprio(1);
#pragma unroll
                for (int sd = 0; sd < 4; sd++) {
                    bf16x8 vf = *(const bf16x8*)&Vts[(sd * 16 + l15) * 128
                                                     + (((kk * 4 + qd) ^ l15) * 8)];
                    o[sd] = __builtin_amdgcn_mfma_f32_16x16x32_bf16(pF, vf, o[sd], 0, 0, 0);
                }
                __builtin_amdgcn_s_setprio(0);
            }
        }

        BAR;   // WAR: next step's V/K staging overwrites buffers just read
    }

    // ---- plain-store O (exclusive q-row ownership) ----
#pragma unroll
    for (int sd = 0; sd < 4; sd++) {
        const int d = sd * 16 + l15;
#pragma unroll
        for (int r = 0; r < 4; r++) {
            const int t = qb + w * 16 + qd * 4 + r;
            out[((size_t)b * T_SEQ + t) * C_EMB + h * 64 + d] = o[sd][r];
        }
    }
}

extern "C" void kernel_launch(void* const* d_in, const int* in_sizes, int n_in,
                              void* d_out, int out_size, void* d_ws, size_t ws_size,
                              hipStream_t stream) {
    const float* x    = (const float*)d_in[0];
    const float* W    = (const float*)d_in[1];
    const float* bias = (const float*)d_in[2];
    float* out        = (float*)d_out;
    bf16*  ws         = (bf16*)d_ws;

    if (ws_size >= WS_NEEDED) {
        bf16* xb = ws + 3 * (size_t)WS_STRIDE;
        bf16* wb = xb + XN;
        cvt_bf16<<<dim3(CVT_GRID), dim3(256), 0, stream>>>(x, W, xb, wb);
        qkv_gemm6<<<dim3(512), dim3(256), 0, stream>>>(xb, wb, bias, ws);
    } else {
        qkv_gemm<<<dim3(768), dim3(256), 0, stream>>>(x, W, bias, ws);
    }
    attn<<<dim3(1024), dim3(256), 0, stream>>>(ws, out);
}